// Round 2
// baseline (445.180 us; speedup 1.0000x reference)
//
#include <hip/hip_runtime.h>
#include <hip/hip_bf16.h>
#include <cstdint>

#define N_TOK 32768
#define CTX   256
#define DIM   1024
#define NH    16
#define HD    64

typedef __attribute__((ext_vector_type(8))) short short8;
typedef __attribute__((ext_vector_type(4))) float f32x4;
typedef __attribute__((ext_vector_type(4))) unsigned short ushort4v;

__device__ inline unsigned short f2bf(float f) {
  union { float f; unsigned int u; } v; v.f = f;
  unsigned int r = v.u + 0x7fffu + ((v.u >> 16) & 1u);
  return (unsigned short)(r >> 16);
}

// ---------------- f32 -> bf16 convert (vectorized, grid-stride) ----------------
__global__ void cvt_kernel(const float* __restrict__ in, unsigned short* __restrict__ out, int n4) {
  int i = blockIdx.x * blockDim.x + threadIdx.x;
  int stride = gridDim.x * blockDim.x;
  for (int j = i; j < n4; j += stride) {
    float4 v = reinterpret_cast<const float4*>(in)[j];
    ushort4v o;
    o.x = f2bf(v.x); o.y = f2bf(v.y); o.z = f2bf(v.z); o.w = f2bf(v.w);
    reinterpret_cast<ushort4v*>(out)[j] = o;
  }
}

// ---------------- small transpose: V[256][1024] -> Vt[1024][256] ----------------
__global__ void transpose_kernel(const unsigned short* __restrict__ Vb, unsigned short* __restrict__ Vtb) {
  int d = blockIdx.x;   // 0..1023
  int c = threadIdx.x;  // 0..255
  Vtb[(size_t)d * CTX + c] = Vb[(size_t)c * DIM + d];
}

// ---------------- bf16 GEMM, C[M,N] = A[M,K] * B[N,K]^T (m97 structure) ----------------
// 128x128 tile, BK=32, 256 threads = 4 waves (2x2), global_load_lds width-16 staging.
template <bool F32OUT>
__global__ __launch_bounds__(256) void gemm_bt(const unsigned short* __restrict__ A,
                                               const unsigned short* __restrict__ B,
                                               void* __restrict__ Cout,
                                               int M, int N, int K) {
  __shared__ unsigned short As[128 * 32];
  __shared__ unsigned short Bs[128 * 32];
  const int tid  = threadIdx.x;
  const int lane = tid & 63;
  const int wid  = tid >> 6;
  const int wr = wid >> 1, wc = wid & 1;
  const int bx = blockIdx.x, by = blockIdx.y;
  const long arow0 = (long)by * 128;
  const long brow0 = (long)bx * 128;
  const int sr = tid >> 2;         // staging row within 64-row pass
  const int sc = (tid & 3) * 8;    // staging col (8 bf16 = 16B)

  f32x4 acc[4][4];
#pragma unroll
  for (int i = 0; i < 4; ++i)
#pragma unroll
    for (int j = 0; j < 4; ++j) acc[i][j] = (f32x4){0.f, 0.f, 0.f, 0.f};

  const int ar = wr * 64 + (lane & 15);
  const int br = wc * 64 + (lane & 15);
  const int kc = (lane >> 4) * 8;

  for (int k0 = 0; k0 < K; k0 += 32) {
#pragma unroll
    for (int pass = 0; pass < 2; ++pass) {
      int r = pass * 64 + sr;
      const unsigned short* ga = &A[(arow0 + r) * K + k0 + sc];
      const unsigned short* gb = &B[(brow0 + r) * K + k0 + sc];
      __builtin_amdgcn_global_load_lds(
          (const __attribute__((address_space(1))) unsigned int*)ga,
          (__attribute__((address_space(3))) unsigned int*)&As[(size_t)tid * 8 + pass * 2048],
          16, 0, 0);
      __builtin_amdgcn_global_load_lds(
          (const __attribute__((address_space(1))) unsigned int*)gb,
          (__attribute__((address_space(3))) unsigned int*)&Bs[(size_t)tid * 8 + pass * 2048],
          16, 0, 0);
    }
    __syncthreads();
    short8 a[4], b[4];
#pragma unroll
    for (int mf = 0; mf < 4; ++mf) a[mf] = *(const short8*)&As[(ar + mf * 16) * 32 + kc];
#pragma unroll
    for (int nf = 0; nf < 4; ++nf) b[nf] = *(const short8*)&Bs[(br + nf * 16) * 32 + kc];
#pragma unroll
    for (int mf = 0; mf < 4; ++mf)
#pragma unroll
      for (int nf = 0; nf < 4; ++nf)
        acc[mf][nf] = __builtin_amdgcn_mfma_f32_16x16x32_bf16(a[mf], b[nf], acc[mf][nf], 0, 0, 0);
    __syncthreads();
  }

  const long row0 = (long)by * 128 + wr * 64 + ((lane >> 4) << 2);
  const long col0 = (long)bx * 128 + wc * 64 + (lane & 15);
  if (F32OUT) {
    float* C = (float*)Cout;
#pragma unroll
    for (int mf = 0; mf < 4; ++mf)
#pragma unroll
      for (int q = 0; q < 4; ++q) {
        float* cp = &C[(row0 + mf * 16 + q) * N + col0];
#pragma unroll
        for (int nf = 0; nf < 4; ++nf) cp[nf * 16] = acc[mf][nf][q];
      }
  } else {
    unsigned short* C = (unsigned short*)Cout;
#pragma unroll
    for (int mf = 0; mf < 4; ++mf)
#pragma unroll
      for (int q = 0; q < 4; ++q) {
        unsigned short* cp = &C[(row0 + mf * 16 + q) * N + col0];
#pragma unroll
        for (int nf = 0; nf < 4; ++nf) cp[nf * 16] = f2bf(acc[mf][nf][q]);
      }
  }
}

// ---------------- fused attention: per (64-row tile, head) ----------------
// S = Q_h K_h^T * 0.125 -> softmax over C=256 -> O = P V_h, written bf16 (in-place over Q).
// RoPE bias b[n,h] is constant along the softmax axis C -> cancels; skipped entirely.
__global__ __launch_bounds__(256) void attn_kernel(const unsigned short* __restrict__ Q,
                                                   const unsigned short* __restrict__ Kc,
                                                   const unsigned short* __restrict__ Vt,
                                                   unsigned short* __restrict__ AO) {
  __shared__ unsigned short KP[256 * 72];  // K_h [256][64+8] ; reused as P [64][264]
  __shared__ unsigned short Vs[64 * 264];  // Vt_h [64][256+8]
  const int tid = threadIdx.x, lane = tid & 63, wid = tid >> 6;
  const int h = blockIdx.y;
  const int n0 = blockIdx.x * 64;

  // stage K_h: rows c (256), cols h*64..h*64+63 (pad row stride 72)
  {
    const int r4 = tid >> 2, c16 = (tid & 3) * 16;   // 4 threads x 16 elems = 64 cols/row
#pragma unroll
    for (int pass = 0; pass < 4; ++pass) {
      int r = pass * 64 + r4;
      const unsigned short* src = &Kc[(size_t)r * DIM + h * HD + c16];
      *(short8*)&KP[r * 72 + c16]     = *(const short8*)&src[0];
      *(short8*)&KP[r * 72 + c16 + 8] = *(const short8*)&src[8];
    }
    // stage Vt_h: rows d (64), cols c (256), pad +8
    const int d = tid >> 2, c0 = (tid & 3) * 64;
#pragma unroll
    for (int j = 0; j < 8; ++j)
      *(short8*)&Vs[d * 264 + c0 + j * 8] = *(const short8*)&Vt[(size_t)(h * HD + d) * CTX + c0 + j * 8];
  }

  // Q A-fragments (wave owns 16 query rows)
  const int qrow = n0 + wid * 16 + (lane & 15);
  const int kc = (lane >> 4) * 8;
  short8 aq0 = *(const short8*)&Q[(size_t)qrow * DIM + h * HD + kc];
  short8 aq1 = *(const short8*)&Q[(size_t)qrow * DIM + h * HD + 32 + kc];
  __syncthreads();

  // S = Q K^T  (16 col-fragments of 16 c's each)
  f32x4 s[16];
#pragma unroll
  for (int cf = 0; cf < 16; ++cf) {
    short8 b0 = *(const short8*)&KP[(cf * 16 + (lane & 15)) * 72 + kc];
    short8 b1 = *(const short8*)&KP[(cf * 16 + (lane & 15)) * 72 + 32 + kc];
    f32x4 z = (f32x4){0.f, 0.f, 0.f, 0.f};
    z = __builtin_amdgcn_mfma_f32_16x16x32_bf16(aq0, b0, z, 0, 0, 0);
    z = __builtin_amdgcn_mfma_f32_16x16x32_bf16(aq1, b1, z, 0, 0, 0);
    s[cf] = z;
  }

  // softmax over 256 (per-lane 16 frags, then 16-lane butterfly). SCALE=0.125 folded into exp2.
  float mx[4] = {-1e30f, -1e30f, -1e30f, -1e30f};
#pragma unroll
  for (int cf = 0; cf < 16; ++cf)
#pragma unroll
    for (int q = 0; q < 4; ++q) mx[q] = fmaxf(mx[q], s[cf][q]);
#pragma unroll
  for (int off = 1; off < 16; off <<= 1)
#pragma unroll
    for (int q = 0; q < 4; ++q) mx[q] = fmaxf(mx[q], __shfl_xor(mx[q], off, 64));

  const float cexp = 0.125f * 1.44269504088896f;  // SCALE * log2(e)
  float rs[4] = {0.f, 0.f, 0.f, 0.f};
#pragma unroll
  for (int cf = 0; cf < 16; ++cf)
#pragma unroll
    for (int q = 0; q < 4; ++q) {
      float p = exp2f((s[cf][q] - mx[q]) * cexp);
      s[cf][q] = p;  // reuse s as P storage
      rs[q] += p;
    }
#pragma unroll
  for (int off = 1; off < 16; off <<= 1)
#pragma unroll
    for (int q = 0; q < 4; ++q) rs[q] += __shfl_xor(rs[q], off, 64);

  __syncthreads();  // all K reads complete before overwriting KP with P

  // write P (bf16) to LDS: row = query row within tile, col = c
  const int prow = wid * 16 + ((lane >> 4) << 2);
#pragma unroll
  for (int cf = 0; cf < 16; ++cf)
#pragma unroll
    for (int q = 0; q < 4; ++q)
      KP[(prow + q) * 264 + cf * 16 + (lane & 15)] = f2bf(s[cf][q]);
  __syncthreads();

  // O = P @ V  (A = P rows, B = Vt rows(d), dot over c)
  f32x4 o[4];
#pragma unroll
  for (int nf = 0; nf < 4; ++nf) o[nf] = (f32x4){0.f, 0.f, 0.f, 0.f};
  const int par = (wid * 16 + (lane & 15)) * 264 + kc;
  const int vbr = (lane & 15) * 264 + kc;
#pragma unroll
  for (int kk = 0; kk < 8; ++kk) {
    short8 ap = *(const short8*)&KP[par + kk * 32];
#pragma unroll
    for (int nf = 0; nf < 4; ++nf) {
      short8 bv = *(const short8*)&Vs[vbr + nf * 16 * 264 + kk * 32];
      o[nf] = __builtin_amdgcn_mfma_f32_16x16x32_bf16(ap, bv, o[nf], 0, 0, 0);
    }
  }

  float rinv[4];
#pragma unroll
  for (int q = 0; q < 4; ++q) rinv[q] = 1.0f / rs[q];
  const size_t orow0 = n0 + wid * 16 + ((lane >> 4) << 2);
  const int ocol = h * HD + (lane & 15);
#pragma unroll
  for (int nf = 0; nf < 4; ++nf)
#pragma unroll
    for (int q = 0; q < 4; ++q)
      AO[(orow0 + q) * DIM + ocol + nf * 16] = f2bf(o[nf][q] * rinv[q]);
}

extern "C" void kernel_launch(void* const* d_in, const int* in_sizes, int n_in,
                              void* d_out, int out_size, void* d_ws, size_t ws_size,
                              hipStream_t stream) {
  (void)in_sizes; (void)n_in; (void)out_size; (void)ws_size;
  const float* x    = (const float*)d_in[0];
  const float* kv   = (const float*)d_in[1];
  // d_in[2] = rope_bias, d_in[7] = Wrope: bias is constant over softmax axis -> unused.
  const float* Wq   = (const float*)d_in[3];
  const float* Wk   = (const float*)d_in[4];
  const float* Wv   = (const float*)d_in[5];
  const float* Wout = (const float*)d_in[6];
  float* out = (float*)d_out;

  char* ws = (char*)d_ws;
  unsigned short* xb  = (unsigned short*)(ws);                 // 64 MB
  unsigned short* Qb  = (unsigned short*)(ws + 67108864);      // 64 MB (reused as attn_out)
  unsigned short* wqb = (unsigned short*)(ws + 134217728);     // 2 MB
  unsigned short* wkb = (unsigned short*)(ws + 136314880);
  unsigned short* wvb = (unsigned short*)(ws + 138412032);
  unsigned short* wob = (unsigned short*)(ws + 140509184);
  unsigned short* kvb = (unsigned short*)(ws + 142606336);     // 0.5 MB
  unsigned short* Kb  = (unsigned short*)(ws + 143130624);
  unsigned short* Vb  = (unsigned short*)(ws + 143654912);
  unsigned short* Vtb = (unsigned short*)(ws + 144179200);

  // f32 -> bf16 converts
  cvt_kernel<<<2048, 256, 0, stream>>>(x,    xb,  (N_TOK * DIM) / 4);
  cvt_kernel<<<256,  256, 0, stream>>>(Wq,   wqb, (DIM * DIM) / 4);
  cvt_kernel<<<256,  256, 0, stream>>>(Wk,   wkb, (DIM * DIM) / 4);
  cvt_kernel<<<256,  256, 0, stream>>>(Wv,   wvb, (DIM * DIM) / 4);
  cvt_kernel<<<256,  256, 0, stream>>>(Wout, wob, (DIM * DIM) / 4);
  cvt_kernel<<<64,   256, 0, stream>>>(kv,   kvb, (CTX * DIM) / 4);

  // K,V projections (tiny), V transpose
  gemm_bt<false><<<dim3(8, 2), 256, 0, stream>>>(kvb, wkb, Kb, CTX, DIM, DIM);
  gemm_bt<false><<<dim3(8, 2), 256, 0, stream>>>(kvb, wvb, Vb, CTX, DIM, DIM);
  transpose_kernel<<<1024, 256, 0, stream>>>(Vb, Vtb);

  // Q projection (big)
  gemm_bt<false><<<dim3(8, 256), 256, 0, stream>>>(xb, wqb, Qb, N_TOK, DIM, DIM);

  // fused attention, in-place attn_out over Qb
  attn_kernel<<<dim3(N_TOK / 64, NH), 256, 0, stream>>>(Qb, Kb, Vtb, Qb);

  // output projection (big, f32 out)
  gemm_bt<true><<<dim3(8, 256), 256, 0, stream>>>(Qb, wob, out, N_TOK, DIM, DIM);
}